// Round 10
// baseline (3696.956 us; speedup 1.0000x reference)
//
#include <hip/hip_runtime.h>
#include <stdint.h>

// RNNTextClassifier: B=64, S=512, E=H=512, NCLS=8
// Round 13: wave-complete outputs, proven staging kept.
// R12 refuted merged-poll + 8-slot ring (revert). R13 removes the last
// post-detect serial component: the cross-wave s_part reduce + B3.
//  - Grid 32 = 2 layers x 4 bg x 4 c-blocks of 128 cols. Block = 512 thr.
//  - Each wave owns ONE 16-col n-tile with FULL K=512 in VGPR weights
//    (wih[16], whhh[16], whhl[16] = 192 VGPRs) -> accumulators are
//    complete sums: finals per-lane (bias+tanh+pack+4 dword publishes)
//    right after the wave's MFMA chain. No s_part, no B3.
//  - Staging/swizzle/poll shapes byte-identical to R8/R11 (split polls,
//    self-contained spins, raw LDS-only barriers, fast_tanh).
//  - Ring 4 slots, tag 3 bits (R8 proven). bp: 4 words at cols c*128.
//  - launch_bounds(512,1): ~250 VGPR alloc without spill (32 blocks).
// Ring: hsl[layer][slot=s&3][row 0..63][col 0..511] u32; tag = s&7.
// ws: hsl 1MB at offset 0 (memset to 0 each launch).

#define BB 64
#define SS 512
#define HH 512

typedef short bf16x8 __attribute__((ext_vector_type(8)));
typedef float f32x4 __attribute__((ext_vector_type(4)));
typedef int i32x4 __attribute__((ext_vector_type(4)));
typedef unsigned int u32;

__device__ __forceinline__ unsigned short f2bf(float f) {
  uint32_t u = __builtin_bit_cast(uint32_t, f);
  u += 0x7FFFu + ((u >> 16) & 1u);
  return (unsigned short)(u >> 16);
}
__device__ __forceinline__ float bf2f(unsigned short h) {
  uint32_t u = ((uint32_t)h) << 16;
  return __builtin_bit_cast(float, u);
}
__device__ __forceinline__ int pack2(unsigned short a, unsigned short b) {
  return (int)(unsigned int)a | ((int)(unsigned int)b << 16);
}
// pack hi halves of two tagged words (a -> low bf16, b -> high bf16)
__device__ __forceinline__ u32 hipack(u32 a, u32 b) {
  return (a >> 16) | (b & 0xFFFF0000u);
}
// pack lo halves (tag bits stripped)
__device__ __forceinline__ u32 lopack(u32 a, u32 b) {
  return (a & 0xFFF8u) | ((b & 0xFFF8u) << 16);
}
__device__ __forceinline__ bool tag4(i32x4 v, u32 t) {
  u32 m = (((u32)v[0] ^ t) | ((u32)v[1] ^ t) | ((u32)v[2] ^ t) | ((u32)v[3] ^ t)) & 7u;
  return m == 0u;
}
// fast tanh: t = sign(v)*(1-e)/(1+e), e = exp(-2|v|). |err| ~1e-7.
__device__ __forceinline__ float fast_tanh(float v) {
  float a = __builtin_fabsf(v);
  float e = __expf(-2.0f * a);
  float t = (1.0f - e) / (1.0f + e);
  return __builtin_copysignf(t, v);
}

// LDS-only barrier: no vmcnt drain (barriers protect LDS staging only).
#define BAR_LDS()                                            \
  do {                                                       \
    asm volatile("s_waitcnt lgkmcnt(0)" ::: "memory");       \
    __builtin_amdgcn_s_barrier();                            \
  } while (0)

// device-coherent (UC) loads/stores: bypass non-common caches
#define UC_LOAD4(dst, ptr) \
  asm volatile("global_load_dwordx4 %0, %1, off sc0 sc1" : "=v"(dst) : "v"(ptr))
#define UC_LOAD1(dst, ptr) \
  asm volatile("global_load_dword %0, %1, off sc0 sc1" : "=v"(dst) : "v"(ptr))
#define UC_STORE1(ptr, v) \
  asm volatile("global_store_dword %0, %1, off sc0 sc1" ::"v"(ptr), "v"(v) : "memory")

__global__ __launch_bounds__(512, 1) void k_rnn(
    const int* __restrict__ x, const float* __restrict__ emb,
    const float* __restrict__ Wih0, const float* __restrict__ Whh0,
    const float* __restrict__ bih0, const float* __restrict__ bhh0,
    const float* __restrict__ Wih1, const float* __restrict__ Whh1,
    const float* __restrict__ bih1, const float* __restrict__ bhh1,
    u32* __restrict__ hsl) {
  const int tid = threadIdx.x;
  const int bid = blockIdx.x;
  const int layer = bid >> 4;  // 0 or 1
  const int lb = bid & 15;
  const int bg = lb >> 2;  // batch group (16 rows)
  const int c = lb & 3;    // 128-col slice
  const int wid = tid >> 6;  // wave -> 16-col n-tile within slice
  const int lane = tid & 63;
  const int r16 = lane & 15, kg = lane >> 4;

  __shared__ __align__(16) unsigned short s_in0[16 * 512];
  __shared__ __align__(16) unsigned short s_Hhi[16 * 512];
  __shared__ __align__(16) unsigned short s_Hlo[16 * 512];

  const float* Wih = layer ? Wih1 : Wih0;
  const float* Whh = layer ? Whh1 : Whh0;
  const float* bi = layer ? bih1 : bih0;
  const float* bh = layer ? bhh1 : bhh0;

  // ---- one-time: full-K W fragments for this wave's 16-col tile ----
  bf16x8 wih[16], whhh[16], whhl[16];
  {
    const int row = c * 128 + wid * 16 + r16;
#pragma unroll
    for (int kt = 0; kt < 16; ++kt) {
      const int k0 = kt * 32 + kg * 8;
      const float* p = Wih + row * 512 + k0;
      bf16x8 v;
#pragma unroll
      for (int j = 0; j < 8; ++j) v[j] = (short)f2bf(p[j]);
      wih[kt] = v;
      const float* q = Whh + row * 512 + k0;
      bf16x8 vh, vl;
#pragma unroll
      for (int j = 0; j < 8; ++j) {
        float f = q[j];
        unsigned short h = f2bf(f);
        vh[j] = (short)h;
        vl[j] = (short)f2bf(f - bf2f(h));
      }
      whhh[kt] = vh;
      whhl[kt] = vl;
    }
  }
  float bv;
  {
    const int gcol = c * 128 + wid * 16 + r16;
    bv = bi[gcol] + bh[gcol];
  }

  const int r_st = tid >> 5;  // staging row 0..15
  const int ch = tid & 31;    // 16-element chunk of 512

  // prefetch in0 for step 1 (layer0: emb gather t=0)
  float4 pf0, pf1, pf2, pf3;
  if (layer == 0) {
    int rid = x[(bg * 16 + r_st) * SS + 0];
    const float4* ep = (const float4*)(emb + (size_t)rid * 512 + ch * 16);
    pf0 = ep[0]; pf1 = ep[1]; pf2 = ep[2]; pf3 = ep[3];
  }

  for (int s = 1; s <= SS; ++s) {
    const u32 exp_h = (u32)((s - 1) & 7);
    const u32* ph = hsl +
        (((size_t)layer * 4 + ((s - 1) & 3)) * 64 + bg * 16 + r_st) * 512 + ch * 16;

    if (layer == 0) {
      // next emb row index (plain load; survives raw barrier un-drained)
      int nrid = 0;
      if (s < SS) nrid = x[(bg * 16 + r_st) * SS + s];

      // ---- stage in0 from prefetched emb f32 (swizzled LDS) ----
      i32x4 v0, v1;
      v0[0] = pack2(f2bf(pf0.x), f2bf(pf0.y));
      v0[1] = pack2(f2bf(pf0.z), f2bf(pf0.w));
      v0[2] = pack2(f2bf(pf1.x), f2bf(pf1.y));
      v0[3] = pack2(f2bf(pf1.z), f2bf(pf1.w));
      v1[0] = pack2(f2bf(pf2.x), f2bf(pf2.y));
      v1[1] = pack2(f2bf(pf2.z), f2bf(pf2.w));
      v1[2] = pack2(f2bf(pf3.x), f2bf(pf3.y));
      v1[3] = pack2(f2bf(pf3.z), f2bf(pf3.w));
      *(i32x4*)(s_in0 + r_st * 512 + (((2 * ch) ^ (r_st & 7)) << 3)) = v0;
      *(i32x4*)(s_in0 + r_st * 512 + (((2 * ch + 1) ^ (r_st & 7)) << 3)) = v1;
      BAR_LDS();  // B1: s_in0 staged

      // issue emb prefetch for s+1 (hides under in0 MFMAs + H poll)
      if (s < SS) {
        const float4* ep = (const float4*)(emb + (size_t)nrid * 512 + ch * 16);
        pf0 = ep[0]; pf1 = ep[1]; pf2 = ep[2]; pf3 = ep[3];
      }
    } else {
      // layer1: poll in0 = out0[s] (self-contained spin, proven shape)
      i32x4 i0 = {0, 0, 0, 0}, i1 = {0, 0, 0, 0}, i2 = {0, 0, 0, 0},
            i3 = {0, 0, 0, 0};
      const u32 exp_i = (u32)(s & 7);
      const u32* pi =
          hsl + (((size_t)(s & 3)) * 64 + bg * 16 + r_st) * 512 + ch * 16;
      while (true) {
        UC_LOAD4(i0, pi);
        UC_LOAD4(i1, pi + 4);
        UC_LOAD4(i2, pi + 8);
        UC_LOAD4(i3, pi + 12);
        asm volatile("s_waitcnt vmcnt(0)"
                     : "+v"(i0), "+v"(i1), "+v"(i2), "+v"(i3)::"memory");
        bool ok = tag4(i0, exp_i) && tag4(i1, exp_i) && tag4(i2, exp_i) &&
                  tag4(i3, exp_i);
        if (__all(ok)) break;
      }
      i32x4 A0 = {(int)hipack(i0[0], i0[1]), (int)hipack(i0[2], i0[3]),
                  (int)hipack(i1[0], i1[1]), (int)hipack(i1[2], i1[3])};
      i32x4 A1 = {(int)hipack(i2[0], i2[1]), (int)hipack(i2[2], i2[3]),
                  (int)hipack(i3[0], i3[1]), (int)hipack(i3[2], i3[3])};
      *(i32x4*)(s_in0 + r_st * 512 + (((2 * ch) ^ (r_st & 7)) << 3)) = A0;
      *(i32x4*)(s_in0 + r_st * 512 + (((2 * ch + 1) ^ (r_st & 7)) << 3)) = A1;
      BAR_LDS();  // B1: s_in0 staged
    }

    // ---- in0 MFMAs: full K for this wave's tile (2 chains of 8) ----
    f32x4 ai0 = {0.f, 0.f, 0.f, 0.f}, ai1 = {0.f, 0.f, 0.f, 0.f};
#pragma unroll
    for (int kt = 0; kt < 16; ++kt) {
      int k8 = kt * 4 + kg;
      bf16x8 ain = __builtin_bit_cast(
          bf16x8, *(const i32x4*)(s_in0 + r16 * 512 + ((k8 ^ (r16 & 7)) << 3)));
      if ((kt & 1) == 0)
        ai0 = __builtin_amdgcn_mfma_f32_16x16x32_bf16(ain, wih[kt], ai0, 0, 0, 0);
      else
        ai1 = __builtin_amdgcn_mfma_f32_16x16x32_bf16(ain, wih[kt], ai1, 0, 0, 0);
    }

    // ============ H poll (self-contained) + stage ============
    f32x4 ahh = {0.f, 0.f, 0.f, 0.f}, ahl = {0.f, 0.f, 0.f, 0.f},
          alh = {0.f, 0.f, 0.f, 0.f};
    if (s > 1) {
      i32x4 h0 = {0, 0, 0, 0}, h1 = {0, 0, 0, 0}, h2 = {0, 0, 0, 0},
            h3 = {0, 0, 0, 0};
      if (layer == 0) {
        const bool need_bp = (s > 4) && (tid < 4);
        const u32 exp_bp = (u32)((s - 4) & 7);
        const u32* pbp = hsl + ((size_t)(4 + ((s - 4) & 3)) * 64 + bg * 16) * 512 +
                         (tid < 4 ? tid * 128 : 0);
        while (true) {
          u32 bpw = 0;
          UC_LOAD4(h0, ph);
          UC_LOAD4(h1, ph + 4);
          UC_LOAD4(h2, ph + 8);
          UC_LOAD4(h3, ph + 12);
          UC_LOAD1(bpw, pbp);
          asm volatile("s_waitcnt vmcnt(0)"
                       : "+v"(h0), "+v"(h1), "+v"(h2), "+v"(h3), "+v"(bpw)::"memory");
          bool ok = tag4(h0, exp_h) && tag4(h1, exp_h) && tag4(h2, exp_h) &&
                    tag4(h3, exp_h) && (!need_bp || ((bpw & 7u) == exp_bp));
          if (__all(ok)) break;
        }
        i32x4 A0 = {(int)hipack(h0[0], h0[1]), (int)hipack(h0[2], h0[3]),
                    (int)hipack(h1[0], h1[1]), (int)hipack(h1[2], h1[3])};
        i32x4 A1 = {(int)hipack(h2[0], h2[1]), (int)hipack(h2[2], h2[3]),
                    (int)hipack(h3[0], h3[1]), (int)hipack(h3[2], h3[3])};
        i32x4 B0 = {(int)lopack(h0[0], h0[1]), (int)lopack(h0[2], h0[3]),
                    (int)lopack(h1[0], h1[1]), (int)lopack(h1[2], h1[3])};
        i32x4 B1v = {(int)lopack(h2[0], h2[1]), (int)lopack(h2[2], h2[3]),
                     (int)lopack(h3[0], h3[1]), (int)lopack(h3[2], h3[3])};
        *(i32x4*)(s_Hhi + r_st * 512 + (((2 * ch) ^ (r_st & 7)) << 3)) = A0;
        *(i32x4*)(s_Hhi + r_st * 512 + (((2 * ch + 1) ^ (r_st & 7)) << 3)) = A1;
        *(i32x4*)(s_Hlo + r_st * 512 + (((2 * ch) ^ (r_st & 7)) << 3)) = B0;
        *(i32x4*)(s_Hlo + r_st * 512 + (((2 * ch + 1) ^ (r_st & 7)) << 3)) = B1v;
      } else {
        while (true) {
          UC_LOAD4(h0, ph);
          UC_LOAD4(h1, ph + 4);
          UC_LOAD4(h2, ph + 8);
          UC_LOAD4(h3, ph + 12);
          asm volatile("s_waitcnt vmcnt(0)"
                       : "+v"(h0), "+v"(h1), "+v"(h2), "+v"(h3)::"memory");
          bool ok = tag4(h0, exp_h) && tag4(h1, exp_h) && tag4(h2, exp_h) &&
                    tag4(h3, exp_h);
          if (__all(ok)) break;
        }
        i32x4 A0 = {(int)hipack(h0[0], h0[1]), (int)hipack(h0[2], h0[3]),
                    (int)hipack(h1[0], h1[1]), (int)hipack(h1[2], h1[3])};
        i32x4 A1 = {(int)hipack(h2[0], h2[1]), (int)hipack(h2[2], h2[3]),
                    (int)hipack(h3[0], h3[1]), (int)hipack(h3[2], h3[3])};
        i32x4 B0 = {(int)lopack(h0[0], h0[1]), (int)lopack(h0[2], h0[3]),
                    (int)lopack(h1[0], h1[1]), (int)lopack(h1[2], h1[3])};
        i32x4 B1v = {(int)lopack(h2[0], h2[1]), (int)lopack(h2[2], h2[3]),
                     (int)lopack(h3[0], h3[1]), (int)lopack(h3[2], h3[3])};
        *(i32x4*)(s_Hhi + r_st * 512 + (((2 * ch) ^ (r_st & 7)) << 3)) = A0;
        *(i32x4*)(s_Hhi + r_st * 512 + (((2 * ch + 1) ^ (r_st & 7)) << 3)) = A1;
        *(i32x4*)(s_Hlo + r_st * 512 + (((2 * ch) ^ (r_st & 7)) << 3)) = B0;
        *(i32x4*)(s_Hlo + r_st * 512 + (((2 * ch + 1) ^ (r_st & 7)) << 3)) = B1v;
      }
    }
    BAR_LDS();  // B2: s_H staged

    // ---- H MFMAs: full K, 3 independent chains (hh, hl, lh) ----
    if (s > 1) {
#pragma unroll
      for (int kt = 0; kt < 16; ++kt) {
        int k8 = kt * 4 + kg;
        bf16x8 ahi = __builtin_bit_cast(
            bf16x8, *(const i32x4*)(s_Hhi + r16 * 512 + ((k8 ^ (r16 & 7)) << 3)));
        bf16x8 alo = __builtin_bit_cast(
            bf16x8, *(const i32x4*)(s_Hlo + r16 * 512 + ((k8 ^ (r16 & 7)) << 3)));
        ahh = __builtin_amdgcn_mfma_f32_16x16x32_bf16(ahi, whhh[kt], ahh, 0, 0, 0);
        ahl = __builtin_amdgcn_mfma_f32_16x16x32_bf16(ahi, whhl[kt], ahl, 0, 0, 0);
        alh = __builtin_amdgcn_mfma_f32_16x16x32_bf16(alo, whhh[kt], alh, 0, 0, 0);
      }
    }

    // ---- finals per lane: complete sums, publish immediately ----
    {
      f32x4 fa = (ai0 + ai1) + ((ahh + ahl) + alh);
      const u32 tag = (u32)(s & 7);
      u32* dst = hsl +
                 (((size_t)layer * 4 + (s & 3)) * 64 + bg * 16 + kg * 4) * 512 +
                 c * 128 + wid * 16 + r16;
#pragma unroll
      for (int j = 0; j < 4; ++j) {
        float t = fast_tanh(fa[j] + bv);
        unsigned short a = f2bf(t);
        unsigned short b = f2bf(t - bf2f(a));
        u32 wv = ((u32)a << 16) | ((u32)b & 0xFFF8u) | tag;
        UC_STORE1(dst + j * 512, wv);
      }
    }
    // fire-and-forget publish; consumers detect via embedded tags
  }
}

__global__ void k_fc(const u32* __restrict__ h1w, const float* __restrict__ fcW,
                     const float* __restrict__ fcb, float* __restrict__ out) {
  int i = threadIdx.x;  // 512 = 64 batch x 8 classes
  int b = i >> 3, cc = i & 7;
  float acc = fcb[cc];
  const u32* ph = h1w + b * 512;
  const float* pw = fcW + cc * 512;
  for (int k = 0; k < 512; k += 4) {
    int4 w4 = *(const int4*)(ph + k);
    float4 wv = *(const float4*)(pw + k);
    acc += (bf2f((unsigned short)((u32)w4.x >> 16)) +
            bf2f((unsigned short)((u32)w4.x & 0xFFF8u))) * wv.x;
    acc += (bf2f((unsigned short)((u32)w4.y >> 16)) +
            bf2f((unsigned short)((u32)w4.y & 0xFFF8u))) * wv.y;
    acc += (bf2f((unsigned short)((u32)w4.z >> 16)) +
            bf2f((unsigned short)((u32)w4.z & 0xFFF8u))) * wv.z;
    acc += (bf2f((unsigned short)((u32)w4.w >> 16)) +
            bf2f((unsigned short)((u32)w4.w & 0xFFF8u))) * wv.w;
  }
  out[b * 8 + cc] = acc;
}

extern "C" void kernel_launch(void* const* d_in, const int* in_sizes, int n_in,
                              void* d_out, int out_size, void* d_ws, size_t ws_size,
                              hipStream_t stream) {
  const int* x = (const int*)d_in[0];
  const float* emb = (const float*)d_in[1];
  const float* Wih0 = (const float*)d_in[2];
  const float* Whh0 = (const float*)d_in[3];
  const float* bih0 = (const float*)d_in[4];
  const float* bhh0 = (const float*)d_in[5];
  const float* Wih1 = (const float*)d_in[6];
  const float* Whh1 = (const float*)d_in[7];
  const float* bih1 = (const float*)d_in[8];
  const float* bhh1 = (const float*)d_in[9];
  const float* fcW = (const float*)d_in[10];
  const float* fcb = (const float*)d_in[11];

  u32* hsl = (u32*)d_ws;  // 2 layers x 4 slots x 64 x 512 u32 = 1 MB

  hipMemsetAsync(hsl, 0, (size_t)2 * 4 * 64 * 512 * 4, stream);
  hipLaunchKernelGGL(k_rnn, dim3(32), dim3(512), 0, stream, x, emb, Wih0, Whh0,
                     bih0, bhh0, Wih1, Whh1, bih1, bhh1, hsl);
  // final h1 = step 512 -> layer1 slot (512&3)==0
  hipLaunchKernelGGL(k_fc, dim3(1), dim3(512), 0, stream,
                     hsl + (size_t)4 * 64 * 512, fcW, fcb, (float*)d_out);
}

// Round 11
// 2069.116 us; speedup vs baseline: 1.7867x; 1.7867x over previous
//
#include <hip/hip_runtime.h>
#include <stdint.h>

// RNNTextClassifier: B=64, S=512, E=H=512, NCLS=8
// Round 14: byte-exact revert to R8 (proven best: 2073.69us).
// Session evidence for why R8 is the plateau:
//  - R9 (per-wave full-K, 256thr): +35% — 8-way LDS write conflicts, half waves.
//  - R10 (per-wave reg-direct H poll): +14% — duplicated UC poll traffic/VALU.
//  - R11 (raw lgkm-only barriers, prefetch placement): neutral — barrier
//    vmcnt drains were never binding.
//  - R12 (merged L1 poll + 8-slot ring): +6% — heavier spin rounds.
//  - R13 (wave-complete 128-col slices): +78% — compiler spilled 192-VGPR
//    weight arrays to scratch (VGPR_Count stayed 128, WRITE +17MB).
// Remaining step time (~4.05us/step) = device-scope publish->MALL->detect
// RT x clique-max(8 publishers), plus ~1us compute/staging. Not reducible
// by reordering (R11), reduce-elimination (R9/R13), poll restructuring
// (R10/R12), or XCD-local sync (R4/R5: livelock / 10x pathological).
// Structure: [stage in0 (+L1: in0 poll)] -> B1 -> [in0 MFMAs] ->
//   [H poll (+L0: bp) + stage H] -> B2 -> [H MFMAs + s_part] -> B3 ->
//   [finals/publish]. Tagged-data protocol: ring slot=s&3, tag=s&7 in
//   lo-word mantissa LSBs; layer0 back-pressure polls layer1 progress.
// ws: hsl 1MB at offset 0 (memset to 0 each launch).

#define BB 64
#define SS 512
#define HH 512

typedef short bf16x8 __attribute__((ext_vector_type(8)));
typedef float f32x4 __attribute__((ext_vector_type(4)));
typedef int i32x4 __attribute__((ext_vector_type(4)));
typedef unsigned int u32;
typedef u32 u32x2 __attribute__((ext_vector_type(2)));

__device__ __forceinline__ unsigned short f2bf(float f) {
  uint32_t u = __builtin_bit_cast(uint32_t, f);
  u += 0x7FFFu + ((u >> 16) & 1u);
  return (unsigned short)(u >> 16);
}
__device__ __forceinline__ float bf2f(unsigned short h) {
  uint32_t u = ((uint32_t)h) << 16;
  return __builtin_bit_cast(float, u);
}
__device__ __forceinline__ int pack2(unsigned short a, unsigned short b) {
  return (int)(unsigned int)a | ((int)(unsigned int)b << 16);
}
// pack hi halves of two words into one u32 (elem a -> low half, b -> high)
__device__ __forceinline__ u32 hipack(u32 a, u32 b) {
  return (a >> 16) | (b & 0xFFFF0000u);
}
// pack lo halves (tag bits stripped)
__device__ __forceinline__ u32 lopack(u32 a, u32 b) {
  return (a & 0xFFF8u) | ((b & 0xFFF8u) << 16);
}
__device__ __forceinline__ bool tag4(i32x4 v, u32 t) {
  u32 m = (((u32)v[0] ^ t) | ((u32)v[1] ^ t) | ((u32)v[2] ^ t) | ((u32)v[3] ^ t)) & 7u;
  return m == 0u;
}
// fast tanh: t = sign(v) * (1 - e)/(1 + e), e = exp(-2|v|). No overflow,
// monotone, |err| ~1e-7. Uses HW v_exp_f32 via __expf.
__device__ __forceinline__ float fast_tanh(float v) {
  float a = __builtin_fabsf(v);
  float e = __expf(-2.0f * a);
  float t = (1.0f - e) / (1.0f + e);
  return __builtin_copysignf(t, v);
}

// device-coherent (UC) loads/stores: bypass non-common caches
#define UC_LOAD4(dst, ptr) \
  asm volatile("global_load_dwordx4 %0, %1, off sc0 sc1" : "=v"(dst) : "v"(ptr))
#define UC_LOAD1(dst, ptr) \
  asm volatile("global_load_dword %0, %1, off sc0 sc1" : "=v"(dst) : "v"(ptr))
#define UC_STORE2(ptr, v) \
  asm volatile("global_store_dwordx2 %0, %1, off sc0 sc1" ::"v"(ptr), "v"(v) : "memory")

__global__ __launch_bounds__(512, 2) void k_rnn(
    const int* __restrict__ x, const float* __restrict__ emb,
    const float* __restrict__ Wih0, const float* __restrict__ Whh0,
    const float* __restrict__ bih0, const float* __restrict__ bhh0,
    const float* __restrict__ Wih1, const float* __restrict__ Whh1,
    const float* __restrict__ bih1, const float* __restrict__ bhh1,
    u32* __restrict__ hsl) {
  const int tid = threadIdx.x;
  const int bid = blockIdx.x;
  const int layer = bid >> 5;  // 0 or 1
  const int lb = bid & 31;
  const int bg = lb >> 3;  // batch group (16 rows)
  const int c = lb & 7;    // hidden slice (64 dims)
  const int wid = tid >> 6;
  const int lane = tid & 63;
  const int kq = wid >> 1;  // K-quarter
  const int nh = wid & 1;   // N-half (32 cols)

  __shared__ __align__(16) unsigned short s_in0[16 * 512];
  __shared__ __align__(16) unsigned short s_Hhi[16 * 512];
  __shared__ __align__(16) unsigned short s_Hlo[16 * 512];
  __shared__ __align__(16) float s_part[4 * 16 * 64];

  const float* Wih = layer ? Wih1 : Wih0;
  const float* Whh = layer ? Whh1 : Whh0;
  const float* bi = layer ? bih1 : bih0;
  const float* bh = layer ? bhh1 : bhh0;

  // ---- one-time: W fragments into VGPRs ----
  bf16x8 wih[2][4], whhh[2][4], whhl[2][4];
  {
    const int r16 = lane & 15, kg = lane >> 4;
#pragma unroll
    for (int nt = 0; nt < 2; ++nt) {
#pragma unroll
      for (int kt = 0; kt < 4; ++kt) {
        int row = c * 64 + nh * 32 + nt * 16 + r16;
        int k0 = kq * 128 + kt * 32 + kg * 8;
        const float* p = Wih + row * 512 + k0;
        bf16x8 v;
#pragma unroll
        for (int j = 0; j < 8; ++j) v[j] = (short)f2bf(p[j]);
        wih[nt][kt] = v;
        const float* q = Whh + row * 512 + k0;
        bf16x8 vh, vl;
#pragma unroll
        for (int j = 0; j < 8; ++j) {
          float f = q[j];
          unsigned short h = f2bf(f);
          vh[j] = (short)h;
          vl[j] = (short)f2bf(f - bf2f(h));
        }
        whhh[nt][kt] = vh;
        whhl[nt][kt] = vl;
      }
    }
  }
  float biasv0, biasv1;
  {
    int na = (tid & 31) * 2;
    biasv0 = bi[c * 64 + na] + bh[c * 64 + na];
    biasv1 = bi[c * 64 + na + 1] + bh[c * 64 + na + 1];
  }

  const int r_st = tid >> 5;  // staging row 0..15
  const int ch = tid & 31;    // 16-element chunk of 512

  // prefetch in0 for step 1 (layer0: emb gather t=0)
  float4 pf0, pf1, pf2, pf3;
  if (layer == 0) {
    int rid = x[(bg * 16 + r_st) * SS + 0];
    const float4* ep = (const float4*)(emb + (size_t)rid * 512 + ch * 16);
    pf0 = ep[0]; pf1 = ep[1]; pf2 = ep[2]; pf3 = ep[3];
  }

  for (int s = 1; s <= SS; ++s) {
    const u32 exp_h = (u32)((s - 1) & 7);
    const u32* ph = hsl +
        (((size_t)layer * 4 + ((s - 1) & 3)) * 64 + bg * 16 + r_st) * 512 + ch * 16;

    // ============ pre-poll phase: h-independent work ============
    if (layer == 0) {
      // stage in0 from prefetched emb f32 (swizzled LDS)
      i32x4 v0, v1;
      v0[0] = pack2(f2bf(pf0.x), f2bf(pf0.y));
      v0[1] = pack2(f2bf(pf0.z), f2bf(pf0.w));
      v0[2] = pack2(f2bf(pf1.x), f2bf(pf1.y));
      v0[3] = pack2(f2bf(pf1.z), f2bf(pf1.w));
      v1[0] = pack2(f2bf(pf2.x), f2bf(pf2.y));
      v1[1] = pack2(f2bf(pf2.z), f2bf(pf2.w));
      v1[2] = pack2(f2bf(pf3.x), f2bf(pf3.y));
      v1[3] = pack2(f2bf(pf3.z), f2bf(pf3.w));
      *(i32x4*)(s_in0 + r_st * 512 + (((2 * ch) ^ (r_st & 7)) << 3)) = v0;
      *(i32x4*)(s_in0 + r_st * 512 + (((2 * ch + 1) ^ (r_st & 7)) << 3)) = v1;
      // issue emb prefetch for s+1 (plain loads; hide under B1+MFMA+poll)
      if (s < SS) {
        int rid = x[(bg * 16 + r_st) * SS + s];
        const float4* ep = (const float4*)(emb + (size_t)rid * 512 + ch * 16);
        pf0 = ep[0]; pf1 = ep[1]; pf2 = ep[2]; pf3 = ep[3];
      }
    } else {
      // layer1: poll in0 = out0[s] (self-contained spin, proven shape)
      i32x4 i0 = {0, 0, 0, 0}, i1 = {0, 0, 0, 0}, i2 = {0, 0, 0, 0}, i3 = {0, 0, 0, 0};
      const u32 exp_i = (u32)(s & 7);
      const u32* pi =
          hsl + (((size_t)(s & 3)) * 64 + bg * 16 + r_st) * 512 + ch * 16;
      while (true) {
        UC_LOAD4(i0, pi);
        UC_LOAD4(i1, pi + 4);
        UC_LOAD4(i2, pi + 8);
        UC_LOAD4(i3, pi + 12);
        asm volatile("s_waitcnt vmcnt(0)"
                     : "+v"(i0), "+v"(i1), "+v"(i2), "+v"(i3)::"memory");
        bool ok = tag4(i0, exp_i) && tag4(i1, exp_i) && tag4(i2, exp_i) &&
                  tag4(i3, exp_i);
        if (__all(ok)) break;
      }
      // stage in0 (hi halves only) into swizzled LDS
      i32x4 A0 = {(int)hipack(i0[0], i0[1]), (int)hipack(i0[2], i0[3]),
                  (int)hipack(i1[0], i1[1]), (int)hipack(i1[2], i1[3])};
      i32x4 A1 = {(int)hipack(i2[0], i2[1]), (int)hipack(i2[2], i2[3]),
                  (int)hipack(i3[0], i3[1]), (int)hipack(i3[2], i3[3])};
      *(i32x4*)(s_in0 + r_st * 512 + (((2 * ch) ^ (r_st & 7)) << 3)) = A0;
      *(i32x4*)(s_in0 + r_st * 512 + (((2 * ch + 1) ^ (r_st & 7)) << 3)) = A1;
    }
    __syncthreads();  // B1: s_in0 staged

    // ---- in0 MFMAs (h-independent: hide under producer publish) ----
    f32x4 acc0 = {0.f, 0.f, 0.f, 0.f};
    f32x4 acc1 = {0.f, 0.f, 0.f, 0.f};
    {
      const int r16 = lane & 15, kg = lane >> 4;
#pragma unroll
      for (int kt = 0; kt < 4; ++kt) {
        int k8 = kq * 16 + kt * 4 + kg;
        bf16x8 ain = __builtin_bit_cast(
            bf16x8, *(const i32x4*)(s_in0 + r16 * 512 + ((k8 ^ (r16 & 7)) << 3)));
        acc0 = __builtin_amdgcn_mfma_f32_16x16x32_bf16(ain, wih[0][kt], acc0, 0, 0, 0);
        acc1 = __builtin_amdgcn_mfma_f32_16x16x32_bf16(ain, wih[1][kt], acc1, 0, 0, 0);
      }
    }

    // ============ H poll (self-contained) + stage ============
    if (s > 1) {
      i32x4 h0 = {0, 0, 0, 0}, h1 = {0, 0, 0, 0}, h2 = {0, 0, 0, 0}, h3 = {0, 0, 0, 0};
      if (layer == 0) {
        const bool need_bp = (s > 4) && (tid < 8);
        const u32 exp_bp = (u32)((s - 4) & 7);
        const u32* pbp = hsl + ((size_t)(4 + ((s - 4) & 3)) * 64 + bg * 16) * 512 +
                         (tid < 8 ? tid * 64 : 0);
        while (true) {
          u32 bpw = 0;
          UC_LOAD4(h0, ph);
          UC_LOAD4(h1, ph + 4);
          UC_LOAD4(h2, ph + 8);
          UC_LOAD4(h3, ph + 12);
          UC_LOAD1(bpw, pbp);
          asm volatile("s_waitcnt vmcnt(0)"
                       : "+v"(h0), "+v"(h1), "+v"(h2), "+v"(h3), "+v"(bpw)::"memory");
          bool ok = tag4(h0, exp_h) && tag4(h1, exp_h) && tag4(h2, exp_h) &&
                    tag4(h3, exp_h) && (!need_bp || ((bpw & 7u) == exp_bp));
          if (__all(ok)) break;
        }
      } else {
        while (true) {
          UC_LOAD4(h0, ph);
          UC_LOAD4(h1, ph + 4);
          UC_LOAD4(h2, ph + 8);
          UC_LOAD4(h3, ph + 12);
          asm volatile("s_waitcnt vmcnt(0)"
                       : "+v"(h0), "+v"(h1), "+v"(h2), "+v"(h3)::"memory");
          bool ok = tag4(h0, exp_h) && tag4(h1, exp_h) && tag4(h2, exp_h) &&
                    tag4(h3, exp_h);
          if (__all(ok)) break;
        }
      }
      // stage H hi/lo (deinterleave tagged words)
      i32x4 A0 = {(int)hipack(h0[0], h0[1]), (int)hipack(h0[2], h0[3]),
                  (int)hipack(h1[0], h1[1]), (int)hipack(h1[2], h1[3])};
      i32x4 A1 = {(int)hipack(h2[0], h2[1]), (int)hipack(h2[2], h2[3]),
                  (int)hipack(h3[0], h3[1]), (int)hipack(h3[2], h3[3])};
      i32x4 B0 = {(int)lopack(h0[0], h0[1]), (int)lopack(h0[2], h0[3]),
                  (int)lopack(h1[0], h1[1]), (int)lopack(h1[2], h1[3])};
      i32x4 B1v = {(int)lopack(h2[0], h2[1]), (int)lopack(h2[2], h2[3]),
                   (int)lopack(h3[0], h3[1]), (int)lopack(h3[2], h3[3])};
      *(i32x4*)(s_Hhi + r_st * 512 + (((2 * ch) ^ (r_st & 7)) << 3)) = A0;
      *(i32x4*)(s_Hhi + r_st * 512 + (((2 * ch + 1) ^ (r_st & 7)) << 3)) = A1;
      *(i32x4*)(s_Hlo + r_st * 512 + (((2 * ch) ^ (r_st & 7)) << 3)) = B0;
      *(i32x4*)(s_Hlo + r_st * 512 + (((2 * ch + 1) ^ (r_st & 7)) << 3)) = B1v;
    }
    __syncthreads();  // B2: s_H staged

    // ---- H MFMAs + partial-sum write ----
    {
      const int r16 = lane & 15, kg = lane >> 4;
      if (s > 1) {
#pragma unroll
        for (int kt = 0; kt < 4; ++kt) {
          int k8 = kq * 16 + kt * 4 + kg;
          bf16x8 ahi = __builtin_bit_cast(
              bf16x8, *(const i32x4*)(s_Hhi + r16 * 512 + ((k8 ^ (r16 & 7)) << 3)));
          bf16x8 alo = __builtin_bit_cast(
              bf16x8, *(const i32x4*)(s_Hlo + r16 * 512 + ((k8 ^ (r16 & 7)) << 3)));
          acc0 = __builtin_amdgcn_mfma_f32_16x16x32_bf16(ahi, whhh[0][kt], acc0, 0, 0, 0);
          acc0 = __builtin_amdgcn_mfma_f32_16x16x32_bf16(ahi, whhl[0][kt], acc0, 0, 0, 0);
          acc0 = __builtin_amdgcn_mfma_f32_16x16x32_bf16(alo, whhh[0][kt], acc0, 0, 0, 0);
          acc1 = __builtin_amdgcn_mfma_f32_16x16x32_bf16(ahi, whhh[1][kt], acc1, 0, 0, 0);
          acc1 = __builtin_amdgcn_mfma_f32_16x16x32_bf16(ahi, whhl[1][kt], acc1, 0, 0, 0);
          acc1 = __builtin_amdgcn_mfma_f32_16x16x32_bf16(alo, whhh[1][kt], acc1, 0, 0, 0);
        }
      }
#pragma unroll
      for (int j = 0; j < 4; ++j) {
        int m = kg * 4 + j;
        int xr = (m >> 2) & 3;
        int n0i = nh * 32 + 0 * 16 + r16;
        int n1i = nh * 32 + 1 * 16 + r16;
        s_part[kq * 1024 + m * 64 + (n0i ^ (xr << 4))] = acc0[j];
        s_part[kq * 1024 + m * 64 + (n1i ^ (xr << 4))] = acc1[j];
      }
    }
    __syncthreads();  // B3

    // ---- finals: reduce, bias, fast-tanh, pack word (hi|lo|tag), publish ----
    {
      int m = tid >> 5, na = (tid & 31) * 2;
      int xr = (m >> 2) & 3;
      float v0 = biasv0, v1 = biasv1;
#pragma unroll
      for (int q2 = 0; q2 < 4; ++q2) {
        const float2* sp =
            (const float2*)(s_part + q2 * 1024 + m * 64 + (na ^ (xr << 4)));
        float2 t = *sp;
        v0 += t.x;
        v1 += t.y;
      }
      v0 = fast_tanh(v0);
      v1 = fast_tanh(v1);
      unsigned short a0 = f2bf(v0), a1 = f2bf(v1);
      unsigned short b0 = f2bf(v0 - bf2f(a0)), b1 = f2bf(v1 - bf2f(a1));
      u32 tag = (u32)(s & 7);
      u32x2 wv;
      wv[0] = ((u32)a0 << 16) | ((u32)b0 & 0xFFF8u) | tag;
      wv[1] = ((u32)a1 << 16) | ((u32)b1 & 0xFFF8u) | tag;
      u32* dst = hsl + (((size_t)layer * 4 + (s & 3)) * 64 + bg * 16 + m) * 512 +
                 c * 64 + na;
      UC_STORE2(dst, wv);
    }
    // no drain, no flag: consumers detect via embedded tags
  }
}

__global__ void k_fc(const u32* __restrict__ h1w, const float* __restrict__ fcW,
                     const float* __restrict__ fcb, float* __restrict__ out) {
  int i = threadIdx.x;  // 512 = 64 batch x 8 classes
  int b = i >> 3, cc = i & 7;
  float acc = fcb[cc];
  const u32* ph = h1w + b * 512;
  const float* pw = fcW + cc * 512;
  for (int k = 0; k < 512; k += 4) {
    int4 w4 = *(const int4*)(ph + k);
    float4 wv = *(const float4*)(pw + k);
    acc += (bf2f((unsigned short)((u32)w4.x >> 16)) +
            bf2f((unsigned short)((u32)w4.x & 0xFFF8u))) * wv.x;
    acc += (bf2f((unsigned short)((u32)w4.y >> 16)) +
            bf2f((unsigned short)((u32)w4.y & 0xFFF8u))) * wv.y;
    acc += (bf2f((unsigned short)((u32)w4.z >> 16)) +
            bf2f((unsigned short)((u32)w4.z & 0xFFF8u))) * wv.z;
    acc += (bf2f((unsigned short)((u32)w4.w >> 16)) +
            bf2f((unsigned short)((u32)w4.w & 0xFFF8u))) * wv.w;
  }
  out[b * 8 + cc] = acc;
}

extern "C" void kernel_launch(void* const* d_in, const int* in_sizes, int n_in,
                              void* d_out, int out_size, void* d_ws, size_t ws_size,
                              hipStream_t stream) {
  const int* x = (const int*)d_in[0];
  const float* emb = (const float*)d_in[1];
  const float* Wih0 = (const float*)d_in[2];
  const float* Whh0 = (const float*)d_in[3];
  const float* bih0 = (const float*)d_in[4];
  const float* bhh0 = (const float*)d_in[5];
  const float* Wih1 = (const float*)d_in[6];
  const float* Whh1 = (const float*)d_in[7];
  const float* bih1 = (const float*)d_in[8];
  const float* bhh1 = (const float*)d_in[9];
  const float* fcW = (const float*)d_in[10];
  const float* fcb = (const float*)d_in[11];

  u32* hsl = (u32*)d_ws;  // 2 layers x 4 slots x 64 x 512 u32 = 1 MB

  hipMemsetAsync(hsl, 0, (size_t)2 * 4 * 64 * 512 * 4, stream);
  hipLaunchKernelGGL(k_rnn, dim3(64), dim3(512), 0, stream, x, emb, Wih0, Whh0,
                     bih0, bhh0, Wih1, Whh1, bih1, bhh1, hsl);
  // final h1 = step 512 -> layer1 slot (512&3)==0
  hipLaunchKernelGGL(k_fc, dim3(1), dim3(512), 0, stream,
                     hsl + (size_t)4 * 64 * 512, fcW, fcb, (float*)d_out);
}

// Round 12
// 1748.146 us; speedup vs baseline: 2.1148x; 1.1836x over previous
//
#include <hip/hip_runtime.h>
#include <stdint.h>

// RNNTextClassifier: B=64, S=512, E=H=512, NCLS=8
// Round 15: wave-specialized PARALLEL polls on the R8 base.
// R8's shape serializes two MALL round-trips per step in EVERY wave
// (in0-poll -> B1 -> MFMA -> h-poll). R15 splits the block: waves 0-3 (A)
// poll+stage in0 (layer1) / stage emb (layer0); waves 4-7 (B) poll+stage
// h[s-1] (+bp). Both spins self-contained (R7 hazard: nothing in-flight
// across barriers); ONE barrier joins them; all 8 waves then run the full
// MFMA phase (roles kq/nh unchanged). Period: 2 serialized RTs -> max(RT).
// Staging by 256-thread groups: chunks {ch+16j} (stride 16) -> 2 lanes per
// bank-quad = 2-way conflict (free, m136) — avoids R9's 8-way mistake.
// launch_bounds(512,1): 64 blocks <= 256 CUs, occupancy cost zero; gives
// VGPR headroom for the 8x i32x4 poll destinations (R13 spill avoided).
// Protocol byte-identical: ring slot=s&3, tag=s&7, bp at s-4, UC sc0 sc1.
// ws: hsl 1MB at offset 0 (memset to 0 each launch).

#define BB 64
#define SS 512
#define HH 512

typedef short bf16x8 __attribute__((ext_vector_type(8)));
typedef float f32x4 __attribute__((ext_vector_type(4)));
typedef int i32x4 __attribute__((ext_vector_type(4)));
typedef unsigned int u32;
typedef u32 u32x2 __attribute__((ext_vector_type(2)));

__device__ __forceinline__ unsigned short f2bf(float f) {
  uint32_t u = __builtin_bit_cast(uint32_t, f);
  u += 0x7FFFu + ((u >> 16) & 1u);
  return (unsigned short)(u >> 16);
}
__device__ __forceinline__ float bf2f(unsigned short h) {
  uint32_t u = ((uint32_t)h) << 16;
  return __builtin_bit_cast(float, u);
}
__device__ __forceinline__ int pack2(unsigned short a, unsigned short b) {
  return (int)(unsigned int)a | ((int)(unsigned int)b << 16);
}
// pack hi halves of two tagged words (a -> low bf16, b -> high bf16)
__device__ __forceinline__ u32 hipack(u32 a, u32 b) {
  return (a >> 16) | (b & 0xFFFF0000u);
}
// pack lo halves (tag bits stripped)
__device__ __forceinline__ u32 lopack(u32 a, u32 b) {
  return (a & 0xFFF8u) | ((b & 0xFFF8u) << 16);
}
__device__ __forceinline__ bool tag4(i32x4 v, u32 t) {
  u32 m = (((u32)v[0] ^ t) | ((u32)v[1] ^ t) | ((u32)v[2] ^ t) | ((u32)v[3] ^ t)) & 7u;
  return m == 0u;
}
// fast tanh: t = sign(v)*(1-e)/(1+e), e = exp(-2|v|). |err| ~1e-7.
__device__ __forceinline__ float fast_tanh(float v) {
  float a = __builtin_fabsf(v);
  float e = __expf(-2.0f * a);
  float t = (1.0f - e) / (1.0f + e);
  return __builtin_copysignf(t, v);
}

// device-coherent (UC) loads/stores: bypass non-common caches
#define UC_LOAD4(dst, ptr) \
  asm volatile("global_load_dwordx4 %0, %1, off sc0 sc1" : "=v"(dst) : "v"(ptr))
#define UC_LOAD1(dst, ptr) \
  asm volatile("global_load_dword %0, %1, off sc0 sc1" : "=v"(dst) : "v"(ptr))
#define UC_STORE2(ptr, v) \
  asm volatile("global_store_dwordx2 %0, %1, off sc0 sc1" ::"v"(ptr), "v"(v) : "memory")

__global__ __launch_bounds__(512, 1) void k_rnn(
    const int* __restrict__ x, const float* __restrict__ emb,
    const float* __restrict__ Wih0, const float* __restrict__ Whh0,
    const float* __restrict__ bih0, const float* __restrict__ bhh0,
    const float* __restrict__ Wih1, const float* __restrict__ Whh1,
    const float* __restrict__ bih1, const float* __restrict__ bhh1,
    u32* __restrict__ hsl) {
  const int tid = threadIdx.x;
  const int bid = blockIdx.x;
  const int layer = bid >> 5;  // 0 or 1
  const int lb = bid & 31;
  const int bg = lb >> 3;  // batch group (16 rows)
  const int c = lb & 7;    // hidden slice (64 dims)
  const int wid = tid >> 6;
  const int lane = tid & 63;
  const int kq = wid >> 1;  // K-quarter (0..3)
  const int nh = wid & 1;   // N-half (32 cols)
  // staging-group index: A = waves 0..3, B = waves 4..7
  const int gt = tid & 255;
  const int gr = gt >> 4;   // row 0..15
  const int gch = gt & 15;  // chunk-base 0..15 (chunks gch+16j, j=0..3)

  __shared__ __align__(16) unsigned short s_in0[16 * 512];
  __shared__ __align__(16) unsigned short s_Hhi[16 * 512];
  __shared__ __align__(16) unsigned short s_Hlo[16 * 512];
  __shared__ __align__(16) float s_part[4 * 16 * 64];

  const float* Wih = layer ? Wih1 : Wih0;
  const float* Whh = layer ? Whh1 : Whh0;
  const float* bi = layer ? bih1 : bih0;
  const float* bh = layer ? bhh1 : bhh0;

  // ---- one-time: W fragments into VGPRs (mapping unchanged from R8) ----
  bf16x8 wih[2][4], whhh[2][4], whhl[2][4];
  {
    const int r16 = lane & 15, kg = lane >> 4;
#pragma unroll
    for (int nt = 0; nt < 2; ++nt) {
#pragma unroll
      for (int kt = 0; kt < 4; ++kt) {
        int row = c * 64 + nh * 32 + nt * 16 + r16;
        int k0 = kq * 128 + kt * 32 + kg * 8;
        const float* p = Wih + row * 512 + k0;
        bf16x8 v;
#pragma unroll
        for (int j = 0; j < 8; ++j) v[j] = (short)f2bf(p[j]);
        wih[nt][kt] = v;
        const float* q = Whh + row * 512 + k0;
        bf16x8 vh, vl;
#pragma unroll
        for (int j = 0; j < 8; ++j) {
          float f = q[j];
          unsigned short h = f2bf(f);
          vh[j] = (short)h;
          vl[j] = (short)f2bf(f - bf2f(h));
        }
        whhh[nt][kt] = vh;
        whhl[nt][kt] = vl;
      }
    }
  }
  float biasv0, biasv1;
  {
    int na = (tid & 31) * 2;
    biasv0 = bi[c * 64 + na] + bh[c * 64 + na];
    biasv1 = bi[c * 64 + na + 1] + bh[c * 64 + na + 1];
  }

  // A-group (layer0): emb prefetch for step 1 — 8 float4 per thread
  float4 pf0, pf1, pf2, pf3, pf4, pf5, pf6, pf7;
  if (layer == 0 && wid < 4) {
    int rid = x[(bg * 16 + gr) * SS + 0];
    const float4* ep = (const float4*)(emb + (size_t)rid * 512);
    pf0 = ep[2 * gch + 0];  pf1 = ep[2 * gch + 1];
    pf2 = ep[2 * gch + 32]; pf3 = ep[2 * gch + 33];
    pf4 = ep[2 * gch + 64]; pf5 = ep[2 * gch + 65];
    pf6 = ep[2 * gch + 96]; pf7 = ep[2 * gch + 97];
  }

  for (int s = 1; s <= SS; ++s) {
    const u32 exp_h = (u32)((s - 1) & 7);

    if (wid < 4) {
      // ================= A-group: in0 path =================
      if (layer == 0) {
        // stage emb (chunks gch, gch+16, gch+32, gch+48) from prefetch
        {
          i32x4 v;
          v[0] = pack2(f2bf(pf0.x), f2bf(pf0.y));
          v[1] = pack2(f2bf(pf0.z), f2bf(pf0.w));
          v[2] = pack2(f2bf(pf1.x), f2bf(pf1.y));
          v[3] = pack2(f2bf(pf1.z), f2bf(pf1.w));
          *(i32x4*)(s_in0 + gr * 512 + (((gch + 0) ^ (gr & 7)) << 3)) = v;
          v[0] = pack2(f2bf(pf2.x), f2bf(pf2.y));
          v[1] = pack2(f2bf(pf2.z), f2bf(pf2.w));
          v[2] = pack2(f2bf(pf3.x), f2bf(pf3.y));
          v[3] = pack2(f2bf(pf3.z), f2bf(pf3.w));
          *(i32x4*)(s_in0 + gr * 512 + (((gch + 16) ^ (gr & 7)) << 3)) = v;
          v[0] = pack2(f2bf(pf4.x), f2bf(pf4.y));
          v[1] = pack2(f2bf(pf4.z), f2bf(pf4.w));
          v[2] = pack2(f2bf(pf5.x), f2bf(pf5.y));
          v[3] = pack2(f2bf(pf5.z), f2bf(pf5.w));
          *(i32x4*)(s_in0 + gr * 512 + (((gch + 32) ^ (gr & 7)) << 3)) = v;
          v[0] = pack2(f2bf(pf6.x), f2bf(pf6.y));
          v[1] = pack2(f2bf(pf6.z), f2bf(pf6.w));
          v[2] = pack2(f2bf(pf7.x), f2bf(pf7.y));
          v[3] = pack2(f2bf(pf7.z), f2bf(pf7.w));
          *(i32x4*)(s_in0 + gr * 512 + (((gch + 48) ^ (gr & 7)) << 3)) = v;
        }
        // issue emb prefetch for s+1 (hides under barrier + MFMA + B-poll)
        if (s < SS) {
          int rid = x[(bg * 16 + gr) * SS + s];
          const float4* ep = (const float4*)(emb + (size_t)rid * 512);
          pf0 = ep[2 * gch + 0];  pf1 = ep[2 * gch + 1];
          pf2 = ep[2 * gch + 32]; pf3 = ep[2 * gch + 33];
          pf4 = ep[2 * gch + 64]; pf5 = ep[2 * gch + 65];
          pf6 = ep[2 * gch + 96]; pf7 = ep[2 * gch + 97];
        }
      } else {
        // layer1: poll in0[s] = out0[s] — 8 loads, self-contained spin
        i32x4 w0 = {0,0,0,0}, w1 = {0,0,0,0}, w2 = {0,0,0,0}, w3 = {0,0,0,0};
        i32x4 w4 = {0,0,0,0}, w5 = {0,0,0,0}, w6 = {0,0,0,0}, w7 = {0,0,0,0};
        const u32 exp_i = (u32)(s & 7);
        const u32* pib =
            hsl + (((size_t)(s & 3)) * 64 + bg * 16 + gr) * 512;
        while (true) {
          UC_LOAD4(w0, pib + 8 * gch + 0);
          UC_LOAD4(w1, pib + 8 * gch + 4);
          UC_LOAD4(w2, pib + 8 * gch + 128);
          UC_LOAD4(w3, pib + 8 * gch + 132);
          UC_LOAD4(w4, pib + 8 * gch + 256);
          UC_LOAD4(w5, pib + 8 * gch + 260);
          UC_LOAD4(w6, pib + 8 * gch + 384);
          UC_LOAD4(w7, pib + 8 * gch + 388);
          asm volatile("s_waitcnt vmcnt(0)"
                       : "+v"(w0), "+v"(w1), "+v"(w2), "+v"(w3), "+v"(w4),
                         "+v"(w5), "+v"(w6), "+v"(w7)::"memory");
          bool ok = tag4(w0, exp_i) && tag4(w1, exp_i) && tag4(w2, exp_i) &&
                    tag4(w3, exp_i) && tag4(w4, exp_i) && tag4(w5, exp_i) &&
                    tag4(w6, exp_i) && tag4(w7, exp_i);
          if (__all(ok)) break;
        }
        // stage hi halves into swizzled s_in0 (chunks gch+16j)
        i32x4 A;
        A[0] = (int)hipack(w0[0], w0[1]); A[1] = (int)hipack(w0[2], w0[3]);
        A[2] = (int)hipack(w1[0], w1[1]); A[3] = (int)hipack(w1[2], w1[3]);
        *(i32x4*)(s_in0 + gr * 512 + (((gch + 0) ^ (gr & 7)) << 3)) = A;
        A[0] = (int)hipack(w2[0], w2[1]); A[1] = (int)hipack(w2[2], w2[3]);
        A[2] = (int)hipack(w3[0], w3[1]); A[3] = (int)hipack(w3[2], w3[3]);
        *(i32x4*)(s_in0 + gr * 512 + (((gch + 16) ^ (gr & 7)) << 3)) = A;
        A[0] = (int)hipack(w4[0], w4[1]); A[1] = (int)hipack(w4[2], w4[3]);
        A[2] = (int)hipack(w5[0], w5[1]); A[3] = (int)hipack(w5[2], w5[3]);
        *(i32x4*)(s_in0 + gr * 512 + (((gch + 32) ^ (gr & 7)) << 3)) = A;
        A[0] = (int)hipack(w6[0], w6[1]); A[1] = (int)hipack(w6[2], w6[3]);
        A[2] = (int)hipack(w7[0], w7[1]); A[3] = (int)hipack(w7[2], w7[3]);
        *(i32x4*)(s_in0 + gr * 512 + (((gch + 48) ^ (gr & 7)) << 3)) = A;
      }
    } else {
      // ================= B-group: h[s-1] path (+bp for layer0) ===========
      if (s > 1) {
        i32x4 w0 = {0,0,0,0}, w1 = {0,0,0,0}, w2 = {0,0,0,0}, w3 = {0,0,0,0};
        i32x4 w4 = {0,0,0,0}, w5 = {0,0,0,0}, w6 = {0,0,0,0}, w7 = {0,0,0,0};
        const u32* phb = hsl +
            (((size_t)layer * 4 + ((s - 1) & 3)) * 64 + bg * 16 + gr) * 512;
        if (layer == 0) {
          const bool need_bp = (s > 4) && (gt < 8);
          const u32 exp_bp = (u32)((s - 4) & 7);
          const u32* pbp = hsl + ((size_t)(4 + ((s - 4) & 3)) * 64 + bg * 16) * 512 +
                           (gt < 8 ? gt * 64 : 0);
          while (true) {
            u32 bpw = 0;
            UC_LOAD4(w0, phb + 8 * gch + 0);
            UC_LOAD4(w1, phb + 8 * gch + 4);
            UC_LOAD4(w2, phb + 8 * gch + 128);
            UC_LOAD4(w3, phb + 8 * gch + 132);
            UC_LOAD4(w4, phb + 8 * gch + 256);
            UC_LOAD4(w5, phb + 8 * gch + 260);
            UC_LOAD4(w6, phb + 8 * gch + 384);
            UC_LOAD4(w7, phb + 8 * gch + 388);
            UC_LOAD1(bpw, pbp);
            asm volatile("s_waitcnt vmcnt(0)"
                         : "+v"(w0), "+v"(w1), "+v"(w2), "+v"(w3), "+v"(w4),
                           "+v"(w5), "+v"(w6), "+v"(w7), "+v"(bpw)::"memory");
            bool ok = tag4(w0, exp_h) && tag4(w1, exp_h) && tag4(w2, exp_h) &&
                      tag4(w3, exp_h) && tag4(w4, exp_h) && tag4(w5, exp_h) &&
                      tag4(w6, exp_h) && tag4(w7, exp_h) &&
                      (!need_bp || ((bpw & 7u) == exp_bp));
            if (__all(ok)) break;
          }
        } else {
          while (true) {
            UC_LOAD4(w0, phb + 8 * gch + 0);
            UC_LOAD4(w1, phb + 8 * gch + 4);
            UC_LOAD4(w2, phb + 8 * gch + 128);
            UC_LOAD4(w3, phb + 8 * gch + 132);
            UC_LOAD4(w4, phb + 8 * gch + 256);
            UC_LOAD4(w5, phb + 8 * gch + 260);
            UC_LOAD4(w6, phb + 8 * gch + 384);
            UC_LOAD4(w7, phb + 8 * gch + 388);
            asm volatile("s_waitcnt vmcnt(0)"
                         : "+v"(w0), "+v"(w1), "+v"(w2), "+v"(w3), "+v"(w4),
                           "+v"(w5), "+v"(w6), "+v"(w7)::"memory");
            bool ok = tag4(w0, exp_h) && tag4(w1, exp_h) && tag4(w2, exp_h) &&
                      tag4(w3, exp_h) && tag4(w4, exp_h) && tag4(w5, exp_h) &&
                      tag4(w6, exp_h) && tag4(w7, exp_h);
            if (__all(ok)) break;
          }
        }
        // stage H hi/lo (chunks gch+16j)
        i32x4 A, B;
        A[0] = (int)hipack(w0[0], w0[1]); A[1] = (int)hipack(w0[2], w0[3]);
        A[2] = (int)hipack(w1[0], w1[1]); A[3] = (int)hipack(w1[2], w1[3]);
        B[0] = (int)lopack(w0[0], w0[1]); B[1] = (int)lopack(w0[2], w0[3]);
        B[2] = (int)lopack(w1[0], w1[1]); B[3] = (int)lopack(w1[2], w1[3]);
        *(i32x4*)(s_Hhi + gr * 512 + (((gch + 0) ^ (gr & 7)) << 3)) = A;
        *(i32x4*)(s_Hlo + gr * 512 + (((gch + 0) ^ (gr & 7)) << 3)) = B;
        A[0] = (int)hipack(w2[0], w2[1]); A[1] = (int)hipack(w2[2], w2[3]);
        A[2] = (int)hipack(w3[0], w3[1]); A[3] = (int)hipack(w3[2], w3[3]);
        B[0] = (int)lopack(w2[0], w2[1]); B[1] = (int)lopack(w2[2], w2[3]);
        B[2] = (int)lopack(w3[0], w3[1]); B[3] = (int)lopack(w3[2], w3[3]);
        *(i32x4*)(s_Hhi + gr * 512 + (((gch + 16) ^ (gr & 7)) << 3)) = A;
        *(i32x4*)(s_Hlo + gr * 512 + (((gch + 16) ^ (gr & 7)) << 3)) = B;
        A[0] = (int)hipack(w4[0], w4[1]); A[1] = (int)hipack(w4[2], w4[3]);
        A[2] = (int)hipack(w5[0], w5[1]); A[3] = (int)hipack(w5[2], w5[3]);
        B[0] = (int)lopack(w4[0], w4[1]); B[1] = (int)lopack(w4[2], w4[3]);
        B[2] = (int)lopack(w5[0], w5[1]); B[3] = (int)lopack(w5[2], w5[3]);
        *(i32x4*)(s_Hhi + gr * 512 + (((gch + 32) ^ (gr & 7)) << 3)) = A;
        *(i32x4*)(s_Hlo + gr * 512 + (((gch + 32) ^ (gr & 7)) << 3)) = B;
        A[0] = (int)hipack(w6[0], w6[1]); A[1] = (int)hipack(w6[2], w6[3]);
        A[2] = (int)hipack(w7[0], w7[1]); A[3] = (int)hipack(w7[2], w7[3]);
        B[0] = (int)lopack(w6[0], w6[1]); B[1] = (int)lopack(w6[2], w6[3]);
        B[2] = (int)lopack(w7[0], w7[1]); B[3] = (int)lopack(w7[2], w7[3]);
        *(i32x4*)(s_Hhi + gr * 512 + (((gch + 48) ^ (gr & 7)) << 3)) = A;
        *(i32x4*)(s_Hlo + gr * 512 + (((gch + 48) ^ (gr & 7)) << 3)) = B;
      }
    }
    __syncthreads();  // B1: s_in0 + s_H staged (A and B joined)

    // ---- full MFMA phase: all 8 waves, roles unchanged ----
    f32x4 acc0 = {0.f, 0.f, 0.f, 0.f};
    f32x4 acc1 = {0.f, 0.f, 0.f, 0.f};
    {
      const int r16 = lane & 15, kg = lane >> 4;
#pragma unroll
      for (int kt = 0; kt < 4; ++kt) {
        int k8 = kq * 16 + kt * 4 + kg;
        bf16x8 ain = __builtin_bit_cast(
            bf16x8, *(const i32x4*)(s_in0 + r16 * 512 + ((k8 ^ (r16 & 7)) << 3)));
        acc0 = __builtin_amdgcn_mfma_f32_16x16x32_bf16(ain, wih[0][kt], acc0, 0, 0, 0);
        acc1 = __builtin_amdgcn_mfma_f32_16x16x32_bf16(ain, wih[1][kt], acc1, 0, 0, 0);
      }
      if (s > 1) {
#pragma unroll
        for (int kt = 0; kt < 4; ++kt) {
          int k8 = kq * 16 + kt * 4 + kg;
          bf16x8 ahi = __builtin_bit_cast(
              bf16x8, *(const i32x4*)(s_Hhi + r16 * 512 + ((k8 ^ (r16 & 7)) << 3)));
          bf16x8 alo = __builtin_bit_cast(
              bf16x8, *(const i32x4*)(s_Hlo + r16 * 512 + ((k8 ^ (r16 & 7)) << 3)));
          acc0 = __builtin_amdgcn_mfma_f32_16x16x32_bf16(ahi, whhh[0][kt], acc0, 0, 0, 0);
          acc0 = __builtin_amdgcn_mfma_f32_16x16x32_bf16(ahi, whhl[0][kt], acc0, 0, 0, 0);
          acc0 = __builtin_amdgcn_mfma_f32_16x16x32_bf16(alo, whhh[0][kt], acc0, 0, 0, 0);
          acc1 = __builtin_amdgcn_mfma_f32_16x16x32_bf16(ahi, whhh[1][kt], acc1, 0, 0, 0);
          acc1 = __builtin_amdgcn_mfma_f32_16x16x32_bf16(ahi, whhl[1][kt], acc1, 0, 0, 0);
          acc1 = __builtin_amdgcn_mfma_f32_16x16x32_bf16(alo, whhh[1][kt], acc1, 0, 0, 0);
        }
      }
#pragma unroll
      for (int j = 0; j < 4; ++j) {
        int m = kg * 4 + j;
        int xr = (m >> 2) & 3;
        int n0i = nh * 32 + 0 * 16 + r16;
        int n1i = nh * 32 + 1 * 16 + r16;
        s_part[kq * 1024 + m * 64 + (n0i ^ (xr << 4))] = acc0[j];
        s_part[kq * 1024 + m * 64 + (n1i ^ (xr << 4))] = acc1[j];
      }
    }
    __syncthreads();  // B3

    // ---- finals: reduce, bias, fast-tanh, pack word (hi|lo|tag), publish ----
    {
      int m = tid >> 5, na = (tid & 31) * 2;
      int xr = (m >> 2) & 3;
      float v0 = biasv0, v1 = biasv1;
#pragma unroll
      for (int q2 = 0; q2 < 4; ++q2) {
        const float2* sp =
            (const float2*)(s_part + q2 * 1024 + m * 64 + (na ^ (xr << 4)));
        float2 t = *sp;
        v0 += t.x;
        v1 += t.y;
      }
      v0 = fast_tanh(v0);
      v1 = fast_tanh(v1);
      unsigned short a0 = f2bf(v0), a1 = f2bf(v1);
      unsigned short b0 = f2bf(v0 - bf2f(a0)), b1 = f2bf(v1 - bf2f(a1));
      u32 tag = (u32)(s & 7);
      u32x2 wv;
      wv[0] = ((u32)a0 << 16) | ((u32)b0 & 0xFFF8u) | tag;
      wv[1] = ((u32)a1 << 16) | ((u32)b1 & 0xFFF8u) | tag;
      u32* dst = hsl + (((size_t)layer * 4 + (s & 3)) * 64 + bg * 16 + m) * 512 +
                 c * 64 + na;
      UC_STORE2(dst, wv);
    }
    // no drain, no flag: consumers detect via embedded tags
  }
}

__global__ void k_fc(const u32* __restrict__ h1w, const float* __restrict__ fcW,
                     const float* __restrict__ fcb, float* __restrict__ out) {
  int i = threadIdx.x;  // 512 = 64 batch x 8 classes
  int b = i >> 3, cc = i & 7;
  float acc = fcb[cc];
  const u32* ph = h1w + b * 512;
  const float* pw = fcW + cc * 512;
  for (int k = 0; k < 512; k += 4) {
    int4 w4 = *(const int4*)(ph + k);
    float4 wv = *(const float4*)(pw + k);
    acc += (bf2f((unsigned short)((u32)w4.x >> 16)) +
            bf2f((unsigned short)((u32)w4.x & 0xFFF8u))) * wv.x;
    acc += (bf2f((unsigned short)((u32)w4.y >> 16)) +
            bf2f((unsigned short)((u32)w4.y & 0xFFF8u))) * wv.y;
    acc += (bf2f((unsigned short)((u32)w4.z >> 16)) +
            bf2f((unsigned short)((u32)w4.z & 0xFFF8u))) * wv.z;
    acc += (bf2f((unsigned short)((u32)w4.w >> 16)) +
            bf2f((unsigned short)((u32)w4.w & 0xFFF8u))) * wv.w;
  }
  out[b * 8 + cc] = acc;
}

extern "C" void kernel_launch(void* const* d_in, const int* in_sizes, int n_in,
                              void* d_out, int out_size, void* d_ws, size_t ws_size,
                              hipStream_t stream) {
  const int* x = (const int*)d_in[0];
  const float* emb = (const float*)d_in[1];
  const float* Wih0 = (const float*)d_in[2];
  const float* Whh0 = (const float*)d_in[3];
  const float* bih0 = (const float*)d_in[4];
  const float* bhh0 = (const float*)d_in[5];
  const float* Wih1 = (const float*)d_in[6];
  const float* Whh1 = (const float*)d_in[7];
  const float* bih1 = (const float*)d_in[8];
  const float* bhh1 = (const float*)d_in[9];
  const float* fcW = (const float*)d_in[10];
  const float* fcb = (const float*)d_in[11];

  u32* hsl = (u32*)d_ws;  // 2 layers x 4 slots x 64 x 512 u32 = 1 MB

  hipMemsetAsync(hsl, 0, (size_t)2 * 4 * 64 * 512 * 4, stream);
  hipLaunchKernelGGL(k_rnn, dim3(64), dim3(512), 0, stream, x, emb, Wih0, Whh0,
                     bih0, bhh0, Wih1, Whh1, bih1, bhh1, hsl);
  // final h1 = step 512 -> layer1 slot (512&3)==0
  hipLaunchKernelGGL(k_fc, dim3(1), dim3(512), 0, stream,
                     hsl + (size_t)4 * 64 * 512, fcW, fcb, (float*)d_out);
}